// Round 7
// baseline (24.616 us; speedup 1.0000x reference)
//
#include <hip/hip_runtime.h>

#define NAG   6144
#define DT    0.01f
#define SOFT  0.25f

typedef __attribute__((ext_vector_type(2))) float f32x2;

#define BLK1  256
#define IPT   2                  // i's per thread in kernel 1
#define IBLK  (BLK1 * IPT)       // 512 i's per block
#define NIB   (NAG / IBLK)       // 12 i-blocks
#define NJC   128                // j-chunks -> 1536 blocks = 6/CU
#define JCH   (NAG / NJC)        // 48 j's per chunk

// ---- kernel 1: partial LJ forces; 2 i's/thread, 2 j's per packed op ----
__global__ __launch_bounds__(BLK1, 6) void lj_partial(
    const float4* __restrict__ pos4,
    const float2* __restrict__ pos2,
    const float*  __restrict__ eps_p,
    const float*  __restrict__ sig_p,
    float4* __restrict__ partial4)
{
    __shared__ __align__(16) float spx[JCH];
    __shared__ __align__(16) float spy[JCH];
    const int tid = threadIdx.x;
    const int jc  = blockIdx.y;
    if (tid < JCH) {
        const float2 pj = pos2[jc * JCH + tid];
        spx[tid] = pj.x;
        spy[tid] = pj.y;
    }
    __syncthreads();

    const float eps  = *eps_p, s = *sig_p;
    const float s2   = s * s, s6 = s2 * s2 * s2;
    const float ke   = 24.0f * eps;
    const f32x2 ks12 = (f32x2)(2.0f * ke * s6 * s6);  // 48*eps*sigma^12
    const f32x2 mks6 = (f32x2)(-ke * s6);             // -24*eps*sigma^6
    const f32x2 softv = (f32x2)(SOFT);

    const int t4 = blockIdx.x * BLK1 + tid;           // i = 2*t4, 2*t4+1
    const float4 p = pos4[t4];
    const f32x2 p0x = (f32x2)(p.x), p0y = (f32x2)(p.y);
    const f32x2 p1x = (f32x2)(p.z), p1y = (f32x2)(p.w);

    f32x2 f0x = 0.f, f0y = 0.f, f1x = 0.f, f1y = 0.f;
#pragma unroll 8
    for (int j = 0; j < JCH; j += 2) {
        const f32x2 xj = *(const f32x2*)&spx[j];      // ds_read_b64 (broadcast)
        const f32x2 yj = *(const f32x2*)&spy[j];
        {   // i0 vs (j, j+1):  c = u^4 * (ks12*u^3 + mks6),  u = 1/(r^2+SOFT)
            const f32x2 dx = p0x - xj, dy = p0y - yj;
            const f32x2 r  = __builtin_elementwise_fma(dy, dy,
                             __builtin_elementwise_fma(dx, dx, softv));
            f32x2 u;
            u.x = __builtin_amdgcn_rcpf(r.x);
            u.y = __builtin_amdgcn_rcpf(r.y);
            const f32x2 u2 = u * u, u3 = u2 * u, u4 = u2 * u2;
            const f32x2 c  = u4 * __builtin_elementwise_fma(ks12, u3, mks6);
            f0x = __builtin_elementwise_fma(c, dx, f0x);   // j==i -> dx=dy=0 -> 0
            f0y = __builtin_elementwise_fma(c, dy, f0y);
        }
        {   // i1 vs (j, j+1)
            const f32x2 dx = p1x - xj, dy = p1y - yj;
            const f32x2 r  = __builtin_elementwise_fma(dy, dy,
                             __builtin_elementwise_fma(dx, dx, softv));
            f32x2 u;
            u.x = __builtin_amdgcn_rcpf(r.x);
            u.y = __builtin_amdgcn_rcpf(r.y);
            const f32x2 u2 = u * u, u3 = u2 * u, u4 = u2 * u2;
            const f32x2 c  = u4 * __builtin_elementwise_fma(ks12, u3, mks6);
            f1x = __builtin_elementwise_fma(c, dx, f1x);
            f1y = __builtin_elementwise_fma(c, dy, f1y);
        }
    }
    partial4[jc * (NAG / 2) + t4] =
        make_float4(f0x.x + f0x.y, f0y.x + f0y.y, f1x.x + f1x.y, f1y.x + f1y.y);
}

// ---- kernel 2: reduce NJC partials + semi-implicit Euler + pack [pos,vel] ----
#define BLK2 64
__global__ __launch_bounds__(BLK2) void lj_integrate(
    const float4* __restrict__ pos4,
    const float4* __restrict__ vel4,
    const float4* __restrict__ partial4,
    float4* __restrict__ out4)
{
    const int t = blockIdx.x * BLK2 + threadIdx.x;    // t in [0, NAG/2)
    float fx0 = 0.f, fy0 = 0.f, fx1 = 0.f, fy1 = 0.f;
#pragma unroll 8
    for (int c = 0; c < NJC; ++c) {
        const float4 q = partial4[c * (NAG / 2) + t];
        fx0 += q.x; fy0 += q.y; fx1 += q.z; fy1 += q.w;
    }
    const float4 pv = pos4[t];
    const float4 vv = vel4[t];
    const float vnx0 = fmaf(DT, fx0, vv.x), vny0 = fmaf(DT, fy0, vv.y);
    const float vnx1 = fmaf(DT, fx1, vv.z), vny1 = fmaf(DT, fy1, vv.w);
    const float pnx0 = fmaf(DT, vnx0, pv.x), pny0 = fmaf(DT, vny0, pv.y);
    const float pnx1 = fmaf(DT, vnx1, pv.z), pny1 = fmaf(DT, vny1, pv.w);
    out4[2 * t]     = make_float4(pnx0, pny0, vnx0, vny0);
    out4[2 * t + 1] = make_float4(pnx1, pny1, vnx1, vny1);
}

// ---- fallback: single-pass (used only if ws_size is too small) ----
__global__ __launch_bounds__(256) void lj_onepass(const float2* __restrict__ pos,
                                                  const float2* __restrict__ vel,
                                                  const float* __restrict__ eps_p,
                                                  const float* __restrict__ sig_p,
                                                  float4* __restrict__ out) {
    __shared__ float2 sp[256];
    const int i = blockIdx.x * 256 + threadIdx.x;
    const float eps  = *eps_p, s = *sig_p;
    const float s2   = s * s, s6 = s2 * s2 * s2;
    const float ke   = 24.0f * eps;
    const float ks12 = 2.0f * ke * s6 * s6;
    const float mks6 = -ke * s6;
    const float2 pi = pos[i];
    float fx = 0.0f, fy = 0.0f;
    for (int tile = 0; tile < NAG; tile += 256) {
        __syncthreads();
        sp[threadIdx.x] = pos[tile + threadIdx.x];
        __syncthreads();
#pragma unroll 8
        for (int j = 0; j < 256; ++j) {
            const float dx = pi.x - sp[j].x, dy = pi.y - sp[j].y;
            const float r  = fmaf(dx, dx, fmaf(dy, dy, SOFT));
            const float u  = __builtin_amdgcn_rcpf(r);
            const float u2 = u * u, u3 = u2 * u, u4 = u2 * u2;
            const float c  = u4 * fmaf(ks12, u3, mks6);
            fx = fmaf(c, dx, fx); fy = fmaf(c, dy, fy);
        }
    }
    const float2 v = vel[i];
    const float vnx = fmaf(DT, fx, v.x), vny = fmaf(DT, fy, v.y);
    const float pnx = fmaf(DT, vnx, pi.x), pny = fmaf(DT, vny, pi.y);
    out[i] = make_float4(pnx, pny, vnx, vny);
}

extern "C" void kernel_launch(void* const* d_in, const int* in_sizes, int n_in,
                              void* d_out, int out_size, void* d_ws, size_t ws_size,
                              hipStream_t stream) {
    const float2* pos2  = (const float2*)d_in[0];
    const float4* pos4  = (const float4*)d_in[0];
    const float2* vel2  = (const float2*)d_in[1];
    const float4* vel4  = (const float4*)d_in[1];
    const float*  eps_p = (const float*)d_in[2];
    const float*  sig_p = (const float*)d_in[3];
    float4* out4 = (float4*)d_out;

    const size_t need = (size_t)NJC * (NAG / 2) * sizeof(float4);
    if (ws_size >= need) {
        float4* partial4 = (float4*)d_ws;
        dim3 grid1(NIB, NJC);
        lj_partial<<<grid1, BLK1, 0, stream>>>(pos4, pos2, eps_p, sig_p, partial4);
        lj_integrate<<<(NAG / 2) / BLK2, BLK2, 0, stream>>>(pos4, vel4, partial4, out4);
    } else {
        lj_onepass<<<NAG / 256, 256, 0, stream>>>(pos2, vel2, eps_p, sig_p, out4);
    }
}

// Round 8
// 18.956 us; speedup vs baseline: 1.2986x; 1.2986x over previous
//
#include <hip/hip_runtime.h>

#define NAG   6144
#define DT    0.01f
#define SOFT  0.25f

#define NJS   32                  // j-slices per i (one per lane-half position)
#define IPB   12                  // i's per block
#define BLK   (NJS * IPB)         // 384 threads = 6 waves
#define NBLK  (NAG / IPB)         // 512 blocks = exactly 2 per CU
#define JITER (NAG / (2 * NJS))   // 96 packed (2-j) iterations per thread

typedef __attribute__((ext_vector_type(2))) float f32x2;

// Single fused kernel: stage all 6144 positions in LDS (48 KB), every thread
// computes one i against an interleaved 1/32 slice of j (2 j's per packed op),
// reduce the 32 slices with shfl_xor inside the wave, integrate, store.
__global__ __launch_bounds__(BLK, 3) void lj_fused(
    const float4* __restrict__ pos4,
    const float2* __restrict__ vel2,
    const float*  __restrict__ eps_p,
    const float*  __restrict__ sig_p,
    float4* __restrict__ out4)
{
    __shared__ __align__(16) float spx[NAG];
    __shared__ __align__(16) float spy[NAG];

    const int tid = threadIdx.x;
    // ---- stage entire pos[] into LDS as SoA (float4 = 2 agents per load) ----
    for (int k = tid; k < NAG / 2; k += BLK) {
        const float4 v = pos4[k];                 // (x0,y0,x1,y1)
        *(f32x2*)&spx[2 * k] = (f32x2){v.x, v.z};
        *(f32x2*)&spy[2 * k] = (f32x2){v.y, v.w};
    }
    __syncthreads();

    const float eps  = *eps_p, s = *sig_p;
    const float s2   = s * s, s6 = s2 * s2 * s2;
    const float ke   = 24.0f * eps;
    const f32x2 ks12 = (f32x2)(2.0f * ke * s6 * s6);   // 48*eps*sigma^12
    const f32x2 mks6 = (f32x2)(-ke * s6);              // -24*eps*sigma^6
    const f32x2 softv = (f32x2)(SOFT);

    const int lane  = tid & 63;
    const int js    = lane & (NJS - 1);                // 0..31
    const int i_idx = (tid >> 6) * 2 + (lane >> 5);    // 0..11
    const int i     = blockIdx.x * IPB + i_idx;

    const f32x2 pix = (f32x2)(spx[i]);                 // broadcast read
    const f32x2 piy = (f32x2)(spy[i]);

    f32x2 fx = 0.f, fy = 0.f;
#pragma unroll 8
    for (int jj = 0; jj < JITER; ++jj) {
        const int j0 = jj * (2 * NJS) + 2 * js;        // wave covers 256B contig
        const f32x2 xj = *(const f32x2*)&spx[j0];      // ds_read_b64, 2/bank
        const f32x2 yj = *(const f32x2*)&spy[j0];
        const f32x2 dx = pix - xj, dy = piy - yj;
        const f32x2 r  = __builtin_elementwise_fma(dy, dy,
                         __builtin_elementwise_fma(dx, dx, softv));
        f32x2 u;
        u.x = __builtin_amdgcn_rcpf(r.x);
        u.y = __builtin_amdgcn_rcpf(r.y);
        const f32x2 u2 = u * u, u3 = u2 * u, u4 = u2 * u2;
        const f32x2 c  = u4 * __builtin_elementwise_fma(ks12, u3, mks6);
        fx = __builtin_elementwise_fma(c, dx, fx);     // j==i -> dx=dy=0 -> +0
        fy = __builtin_elementwise_fma(c, dy, fy);
    }

    // ---- reduce the 32 j-slices: masks <32 stay within the 32-lane group ----
    float sfx = fx.x + fx.y;
    float sfy = fy.x + fy.y;
#pragma unroll
    for (int m = 16; m >= 1; m >>= 1) {
        sfx += __shfl_xor(sfx, m, 64);
        sfy += __shfl_xor(sfy, m, 64);
    }

    if (js == 0) {                                     // 2 lanes per wave
        const float2 v  = vel2[i];
        const float vnx = fmaf(DT, sfx, v.x);
        const float vny = fmaf(DT, sfy, v.y);
        const float pnx = fmaf(DT, vnx, spx[i]);
        const float pny = fmaf(DT, vny, spy[i]);
        out4[i] = make_float4(pnx, pny, vnx, vny);
    }
}

extern "C" void kernel_launch(void* const* d_in, const int* in_sizes, int n_in,
                              void* d_out, int out_size, void* d_ws, size_t ws_size,
                              hipStream_t stream) {
    const float4* pos4  = (const float4*)d_in[0];
    const float2* vel2  = (const float2*)d_in[1];
    const float*  eps_p = (const float*)d_in[2];
    const float*  sig_p = (const float*)d_in[3];
    float4* out4 = (float4*)d_out;
    (void)d_ws; (void)ws_size;

    lj_fused<<<NBLK, BLK, 0, stream>>>(pos4, vel2, eps_p, sig_p, out4);
}

// Round 9
// 18.773 us; speedup vs baseline: 1.3112x; 1.0098x over previous
//
#include <hip/hip_runtime.h>

#define NAG   6144
#define DT    0.01f
#define SOFT  0.25f

#define BLK   384                    // 6 waves
#define IPW   2                      // i's per thread (register tiling)
#define IPB   ((BLK / 64) * IPW)     // 12 i's per block
#define NBLK  (NAG / IPB)            // 512 blocks = 2 per CU
#define JITER (NAG / 128)            // 48 iters: 64 lane-slices x 2 j's per iter

typedef __attribute__((ext_vector_type(2))) float f32x2;

// Fused all-pairs LJ + Euler step. All positions staged SoA in LDS (48 KB).
// Each wave owns 2 consecutive i's; each lane handles a 1/64 j-slice, 2 j's
// per packed iteration, one j-read feeding both i's (halves LDS traffic).
// Reciprocal via batch inversion: 1 rcp + 3 mul for 2 j's (was 2 rcp).
__global__ __launch_bounds__(BLK, 3) void lj_fused(
    const float4* __restrict__ pos4,
    const float2* __restrict__ vel2,
    const float*  __restrict__ eps_p,
    const float*  __restrict__ sig_p,
    float4* __restrict__ out4)
{
    __shared__ __align__(16) float spx[NAG];
    __shared__ __align__(16) float spy[NAG];

    const int tid = threadIdx.x;
    for (int k = tid; k < NAG / 2; k += BLK) {        // 8 float4 loads/thread
        const float4 v = pos4[k];                     // (x0,y0,x1,y1)
        *(f32x2*)&spx[2 * k] = (f32x2){v.x, v.z};
        *(f32x2*)&spy[2 * k] = (f32x2){v.y, v.w};
    }
    __syncthreads();

    const float eps  = *eps_p, s = *sig_p;
    const float s2   = s * s, s6 = s2 * s2 * s2;
    const float ke   = 24.0f * eps;
    const f32x2 ks12 = (f32x2)(2.0f * ke * s6 * s6);  // 48*eps*sigma^12
    const f32x2 mks6 = (f32x2)(-ke * s6);             // -24*eps*sigma^6
    const f32x2 softv = (f32x2)(SOFT);

    const int lane = tid & 63;
    const int wid  = tid >> 6;                        // 0..5
    const int i0   = blockIdx.x * IPB + 2 * wid;
    const int i1   = i0 + 1;

    const f32x2 p0x = (f32x2)(spx[i0]), p0y = (f32x2)(spy[i0]);  // broadcast
    const f32x2 p1x = (f32x2)(spx[i1]), p1y = (f32x2)(spy[i1]);

    f32x2 f0x = 0.f, f0y = 0.f, f1x = 0.f, f1y = 0.f;
#pragma unroll 8
    for (int jj = 0; jj < JITER; ++jj) {
        const int j0 = jj * 128 + 2 * lane;           // wave covers 512B contig
        const f32x2 xj = *(const f32x2*)&spx[j0];     // ds_read_b64
        const f32x2 yj = *(const f32x2*)&spy[j0];
        {   // i0 vs (j0, j0+1)
            const f32x2 dx = p0x - xj, dy = p0y - yj;
            const f32x2 r  = __builtin_elementwise_fma(dy, dy,
                             __builtin_elementwise_fma(dx, dx, softv));
            const float t  = __builtin_amdgcn_rcpf(r.x * r.y);
            const f32x2 u  = {t * r.y, t * r.x};      // (1/r.x, 1/r.y)
            const f32x2 u2 = u * u, u3 = u2 * u, u4 = u2 * u2;
            const f32x2 c  = u4 * __builtin_elementwise_fma(ks12, u3, mks6);
            f0x = __builtin_elementwise_fma(c, dx, f0x);  // j==i -> dx=dy=0
            f0y = __builtin_elementwise_fma(c, dy, f0y);
        }
        {   // i1 vs (j0, j0+1) — reuses the same j-read
            const f32x2 dx = p1x - xj, dy = p1y - yj;
            const f32x2 r  = __builtin_elementwise_fma(dy, dy,
                             __builtin_elementwise_fma(dx, dx, softv));
            const float t  = __builtin_amdgcn_rcpf(r.x * r.y);
            const f32x2 u  = {t * r.y, t * r.x};
            const f32x2 u2 = u * u, u3 = u2 * u, u4 = u2 * u2;
            const f32x2 c  = u4 * __builtin_elementwise_fma(ks12, u3, mks6);
            f1x = __builtin_elementwise_fma(c, dx, f1x);
            f1y = __builtin_elementwise_fma(c, dy, f1y);
        }
    }

    // ---- full-wave reduction of the 64 j-slices ----
    float s0x = f0x.x + f0x.y, s0y = f0y.x + f0y.y;
    float s1x = f1x.x + f1x.y, s1y = f1y.x + f1y.y;
#pragma unroll
    for (int m = 32; m >= 1; m >>= 1) {
        s0x += __shfl_xor(s0x, m, 64);
        s0y += __shfl_xor(s0y, m, 64);
        s1x += __shfl_xor(s1x, m, 64);
        s1y += __shfl_xor(s1y, m, 64);
    }

    if (lane == 0) {
        const float2 v0 = vel2[i0];
        const float2 v1 = vel2[i1];
        const float vnx0 = fmaf(DT, s0x, v0.x), vny0 = fmaf(DT, s0y, v0.y);
        const float vnx1 = fmaf(DT, s1x, v1.x), vny1 = fmaf(DT, s1y, v1.y);
        const float pnx0 = fmaf(DT, vnx0, spx[i0]), pny0 = fmaf(DT, vny0, spy[i0]);
        const float pnx1 = fmaf(DT, vnx1, spx[i1]), pny1 = fmaf(DT, vny1, spy[i1]);
        out4[i0] = make_float4(pnx0, pny0, vnx0, vny0);
        out4[i1] = make_float4(pnx1, pny1, vnx1, vny1);
    }
}

extern "C" void kernel_launch(void* const* d_in, const int* in_sizes, int n_in,
                              void* d_out, int out_size, void* d_ws, size_t ws_size,
                              hipStream_t stream) {
    const float4* pos4  = (const float4*)d_in[0];
    const float2* vel2  = (const float2*)d_in[1];
    const float*  eps_p = (const float*)d_in[2];
    const float*  sig_p = (const float*)d_in[3];
    float4* out4 = (float4*)d_out;
    (void)d_ws; (void)ws_size;

    lj_fused<<<NBLK, BLK, 0, stream>>>(pos4, vel2, eps_p, sig_p, out4);
}